// Round 18
// baseline (540.342 us; speedup 1.0000x reference)
//
#include <hip/hip_runtime.h>
#include <math.h>

#define BB 16
#define NN 2048
#define BN_EPS_ 1e-5f

typedef __attribute__((ext_vector_type(8))) short short8v;   // 8 bf16 (4 VGPRs)
typedef __attribute__((ext_vector_type(4))) float f32x4;

__device__ __forceinline__ unsigned short f2bf(float x){
  unsigned u = __float_as_uint(x);
  u += 0x7fffu + ((u >> 16) & 1u);          // round-to-nearest-even
  return (unsigned short)(u >> 16);
}
__device__ __forceinline__ float bf2f(unsigned short h){
  return __uint_as_float(((unsigned)h) << 16);
}

// ---------------- density v7: 512 threads, wave-per-row phases, inline point-normalize ----------------
#define DG 8
__global__ __launch_bounds__(512) void density7_kernel(const float* __restrict__ x,
        float* __restrict__ inv, float* __restrict__ blockmax){
  __shared__ float us0[NN], us1[NN], us2[NN];      // 24 KiB
  __shared__ unsigned int hist[DG][256];           // 8 KiB
  __shared__ float buf[DG][128];                   // 4 KiB
  __shared__ unsigned int bufcnt[DG];
  __shared__ unsigned int bB[DG], bC0[DG];
  __shared__ float partial[DG][8];
  __shared__ float rowiv[DG];
  const int b = blockIdx.y;
  const float* xb = x + (size_t)b*3*NN;
  const int t = threadIdx.x;                       // 0..511
  {
    float4 v0 = ((const float4*)xb)[t];
    float4 v1 = ((const float4*)(xb + NN))[t];
    float4 v2 = ((const float4*)(xb + 2*NN))[t];
    float4 rr;
    rr.x = rsqrtf(v0.x*v0.x + v1.x*v1.x + v2.x*v2.x);
    rr.y = rsqrtf(v0.y*v0.y + v1.y*v1.y + v2.y*v2.y);
    rr.z = rsqrtf(v0.z*v0.z + v1.z*v1.z + v2.z*v2.z);
    rr.w = rsqrtf(v0.w*v0.w + v1.w*v1.w + v2.w*v2.w);
    v0.x*=rr.x; v0.y*=rr.y; v0.z*=rr.z; v0.w*=rr.w;
    v1.x*=rr.x; v1.y*=rr.y; v1.z*=rr.z; v1.w*=rr.w;
    v2.x*=rr.x; v2.y*=rr.y; v2.z*=rr.z; v2.w*=rr.w;
    ((float4*)us0)[t] = v0; ((float4*)us1)[t] = v1; ((float4*)us2)[t] = v2;
  }
  #pragma unroll
  for (int i = 0; i < 4; ++i) ((unsigned*)hist)[t + 512*i] = 0u;
  if (t < DG) bufcnt[t] = 0u;
  __syncthreads();
  float m0[4], m1[4], m2[4];
  #pragma unroll
  for (int i = 0; i < 4; ++i){
    int c = t + 512*i;
    m0[i] = us0[c]; m1[i] = us1[c]; m2[i] = us2[c];
  }
  const int r0 = blockIdx.x * DG;
  float dd[DG][4]; unsigned qp[DG];
  #pragma unroll
  for (int j = 0; j < DG; ++j){
    float ru0 = us0[r0+j], ru1 = us1[r0+j], ru2 = us2[r0+j];
    unsigned q0 = 0u;
    #pragma unroll
    for (int i = 0; i < 4; ++i){
      float d = 1.0f - (ru0*m0[i] + ru1*m1[i] + ru2*m2[i]);
      dd[j][i] = d;
      int q = (int)(d * 128.0f);
      q = q < 0 ? 0 : (q > 255 ? 255 : q);
      q0 |= (unsigned)q << (8*i);
      atomicAdd(&hist[j][q], 1u);
    }
    qp[j] = q0;
  }
  __syncthreads();

  const int wave = t >> 6, lane = t & 63;
  {
    const int j = wave;
    uint4 cc = *(const uint4*)&hist[j][lane*4];
    unsigned tl = cc.x + cc.y + cc.z + cc.w;
    unsigned inc = tl;
    #pragma unroll
    for (int off = 1; off < 64; off <<= 1){
      unsigned o = __shfl_up(inc, off);
      if (lane >= off) inc += o;
    }
    unsigned base = inc - tl;
    if (base < 32u && base + tl >= 32u){
      unsigned cum = base;
      if (cum < 32u && cum + cc.x >= 32u){ bB[j] = lane*4 + 0; bC0[j] = cum; } cum += cc.x;
      if (cum < 32u && cum + cc.y >= 32u){ bB[j] = lane*4 + 1; bC0[j] = cum; } cum += cc.y;
      if (cum < 32u && cum + cc.z >= 32u){ bB[j] = lane*4 + 2; bC0[j] = cum; } cum += cc.z;
      if (cum < 32u && cum + cc.w >= 32u){ bB[j] = lane*4 + 3; bC0[j] = cum; } cum += cc.w;
    }
  }
  __syncthreads();

  #pragma unroll
  for (int j = 0; j < DG; ++j){
    const int B = (int)bB[j];
    float s = 0.0f;
    #pragma unroll
    for (int i = 0; i < 4; ++i){
      float d = dd[j][i];
      int q = (int)((qp[j] >> (8*i)) & 255u);
      if (q < B) s += d;
      else if (q == B){
        unsigned slot = atomicAdd(&bufcnt[j], 1u);
        if (slot < 128u) buf[j][slot] = d;
      }
    }
    #pragma unroll
    for (int off = 32; off > 0; off >>= 1) s += __shfl_xor(s, off);
    if (lane == 0) partial[j][wave] = s;
  }
  __syncthreads();

  {
    const int j = wave;
    float total = 0.0f;
    #pragma unroll
    for (int wv = 0; wv < 8; ++wv) total += partial[j][wv];
    int cnt = (int)bufcnt[j]; if (cnt > 128) cnt = 128;
    const int rr = 32 - (int)bC0[j];
    float v1 = (lane      < cnt) ? buf[j][lane]      : 0.0f;
    float v2 = (lane + 64 < cnt) ? buf[j][lane + 64] : 0.0f;
    int rk1 = 0, rk2 = 0;
    for (int k = 0; k < cnt; ++k){
      float vk = buf[j][k];
      rk1 += ((vk < v1) || (vk == v1 && k < lane)) ? 1 : 0;
      rk2 += ((vk < v2) || (vk == v2 && k < lane + 64)) ? 1 : 0;
    }
    float contrib = ((lane      < cnt) && (rk1 < rr)) ? v1 : 0.0f;
    contrib      += ((lane + 64 < cnt) && (rk2 < rr)) ? v2 : 0.0f;
    #pragma unroll
    for (int off = 32; off > 0; off >>= 1) contrib += __shfl_xor(contrib, off);
    total += contrib;
    if (lane == 0){
      float iv = 32.0f / total;
      inv[b*NN + r0 + j] = iv;
      rowiv[j] = iv;
    }
  }
  __syncthreads();
  if (t == 0){
    float m = rowiv[0];
    #pragma unroll
    for (int j = 1; j < DG; ++j) m = fmaxf(m, rowiv[j]);
    blockmax[blockIdx.y * gridDim.x + blockIdx.x] = m;
  }
}

__global__ __launch_bounds__(256) void finalize_max_kernel(const float* __restrict__ blockmax,
        float* __restrict__ maxout){
  __shared__ float pw[4];
  const int t = threadIdx.x;
  float m = 0.0f;
  #pragma unroll
  for (int i = 0; i < 16; ++i) m = fmaxf(m, blockmax[t + 256*i]);
  #pragma unroll
  for (int off = 32; off > 0; off >>= 1) m = fmaxf(m, __shfl_xor(m, off));
  if ((t & 63) == 0) pw[t >> 6] = m;
  __syncthreads();
  if (t == 0) *maxout = fmaxf(fmaxf(pw[0], pw[1]), fmaxf(pw[2], pw[3]));
}

// --------- Zinv for ALL 4 layers: out[l][b][r] = 1/Σ_m exp(s_l·d_r·d_m), s_l incl. 1/mx² ---------
__global__ __launch_bounds__(256) void zrow4_kernel(const float* __restrict__ dens,
      const float* __restrict__ maxval,
      const float* __restrict__ w0, const float* __restrict__ w1,
      const float* __restrict__ w2, const float* __restrict__ w3,
      float* __restrict__ out){
  __shared__ float ds[NN];
  const int b = blockIdx.y, t = threadIdx.x;
  float mx = *maxval;
  float r2 = 1.0f / (mx*mx);
  float s0=0.f, s1=0.f, s2=0.f, s3=0.f;
  for (int k = 0; k < 16; ++k){ float w = w0[k]; s0 += w*w; }
  for (int k = 0; k < 16; ++k){ float w = w1[k]; s1 += w*w; }
  for (int k = 0; k < 16; ++k){ float w = w2[k]; s2 += w*w; }
  for (int k = 0; k < 32; ++k){ float w = w3[k]; s3 += w*w; }
  s0 *= r2; s1 *= r2; s2 *= r2; s3 *= r2;
  #pragma unroll
  for (int i = 0; i < NN/256; ++i) ds[t + 256*i] = dens[b*NN + t + 256*i];
  __syncthreads();
  const int wave = t >> 6, lane = t & 63;
  const int RPB = NN / gridDim.x;
  const int r0 = blockIdx.x * RPB;
  for (int r = r0 + wave; r < r0 + RPB; r += 4){
    float dr = ds[r];
    float a0 = s0*dr, a1 = s1*dr, a2 = s2*dr, a3 = s3*dr;
    float q0=0.f, q1=0.f, q2=0.f, q3=0.f;
    #pragma unroll
    for (int i = 0; i < NN/64; ++i){
      float dm = ds[lane + 64*i];
      q0 += __expf(a0*dm); q1 += __expf(a1*dm);
      q2 += __expf(a2*dm); q3 += __expf(a3*dm);
    }
    #pragma unroll
    for (int off = 32; off > 0; off >>= 1){
      q0 += __shfl_xor(q0, off); q1 += __shfl_xor(q1, off);
      q2 += __shfl_xor(q2, off); q3 += __shfl_xor(q3, off);
    }
    if (lane == 0){
      out[0*(size_t)BB*NN + b*NN + r] = 1.0f/q0;
      out[1*(size_t)BB*NN + b*NN + r] = 1.0f/q1;
      out[2*(size_t)BB*NN + b*NN + r] = 1.0f/q2;
      out[3*(size_t)BB*NN + b*NN + r] = 1.0f/q3;
    }
  }
}

// --------- MFMA attention GEMM v9: E computed IN REGISTERS (no E LDS), colsum in registers ---------
// raw_h[c,m] = Σ_{n in half h} A[c,n]·eh[n,m]; row C = partial colsum (= Σ bf2f(eh)).
// A pre-split bf16 hi/lo in global; staged via coalesced copy to XOR-swizzled LDS (only A).
template<int C>
__global__ __launch_bounds__(256, 2) void attn_mfma_kernel(const unsigned short* __restrict__ Ah,
      const unsigned short* __restrict__ Al, const float* __restrict__ dens,
      const float* __restrict__ zinv, const float* __restrict__ wqk, int K,
      const float* __restrict__ maxval, unsigned short* __restrict__ raw){
  constexpr int RA = C + 16;          // raw rows (colsum row at C)
  constexpr int RH = C / 32;          // A row-tiles per wave
  __shared__ __align__(16) unsigned short ah[C][64], al[C][64];   // 32 KB (C=128) / 16 KB
  const int id = blockIdx.x;
  const int b  = (id & 7) + ((id >> 9) << 3);
  const int inner = (id >> 3) & 63;
  const int m0 = (inner & 31) * 64;
  const int nh = inner >> 5;
  const size_t HS = (size_t)BB*RA*NN;            // half-buffer stride (ushorts)
  const int t = threadIdx.x;
  float s = 0.0f;
  for (int k = 0; k < K; ++k){ float w = wqk[k]; s += w*w; }
  { float mx = *maxval; s = s / (mx*mx); }
  const float* db = dens + b*NN;
  const float* zb = zinv + b*NN;
  const unsigned short* Abh = Ah + (size_t)b*C*NN;
  const unsigned short* Abl = Al + (size_t)b*C*NN;
  const int l = t & 63, w = t >> 6;
  const int rw = w & 1, cw = w >> 1;               // 2x2 wave quadrant
  const int fc = l & 15, g = l >> 4;
  const unsigned swr = (unsigned)((fc & 7) << 4);  // frag read swizzle
  float dm[2];                                     // this lane's two B-column densities (x s)
  dm[0] = s * db[m0 + (2*cw+0)*16 + fc];
  dm[1] = s * db[m0 + (2*cw+1)*16 + fc];
  f32x4 acc[RH][2];
  float cs[2] = {0.f, 0.f};
  #pragma unroll
  for (int i = 0; i < RH; ++i){ acc[i][0] = (f32x4){0.f,0.f,0.f,0.f}; acc[i][1] = (f32x4){0.f,0.f,0.f,0.f}; }

  for (int n0 = nh*(NN/2); n0 < (nh+1)*(NN/2); n0 += 64){
    __syncthreads();
    // ---- stage A: coalesced uint4 copy from precomputed global hi/lo, swizzled write
    #pragma unroll
    for (int i = 0; i < C*8/256; ++i){
      int idx = t + 256*i;
      int row = idx >> 3, c8 = (idx & 7) * 8;
      unsigned off = (unsigned)(row*128) + (((unsigned)(c8*2)) ^ ((unsigned)((row&7)<<4)));
      *(uint4*)((char*)ah + off) = *(const uint4*)(Abh + (size_t)row*NN + n0 + c8);
      *(uint4*)((char*)al + off) = *(const uint4*)(Abl + (size_t)row*NN + n0 + c8);
    }
    __syncthreads();
    // ---- MFMA with in-register E fragments (8 consecutive k per lane per ct)
    #pragma unroll
    for (int kk = 0; kk < 2; ++kk){
      const int kb = n0 + kk*32 + g*8;
      float4 dn0 = *(const float4*)(db + kb);
      float4 dn1 = *(const float4*)(db + kb + 4);
      float4 zv0 = *(const float4*)(zb + kb);
      float4 zv1 = *(const float4*)(zb + kb + 4);
      unsigned ko = ((unsigned)((kk*32 + g*8)*2)) ^ swr;
      short8v ai[RH], au[RH];
      #pragma unroll
      for (int i = 0; i < RH; ++i){
        unsigned aoff = (unsigned)((rw*(C/2) + i*16 + fc)*128) + ko;
        ai[i] = *(const short8v*)((const char*)ah + aoff);
        au[i] = *(const short8v*)((const char*)al + aoff);
      }
      #pragma unroll
      for (int ct = 0; ct < 2; ++ct){
        float e[8];
        e[0] = zv0.x*__expf(dn0.x*dm[ct]); e[1] = zv0.y*__expf(dn0.y*dm[ct]);
        e[2] = zv0.z*__expf(dn0.z*dm[ct]); e[3] = zv0.w*__expf(dn0.w*dm[ct]);
        e[4] = zv1.x*__expf(dn1.x*dm[ct]); e[5] = zv1.y*__expf(dn1.y*dm[ct]);
        e[6] = zv1.z*__expf(dn1.z*dm[ct]); e[7] = zv1.w*__expf(dn1.w*dm[ct]);
        short8v bh;
        float se = 0.0f;
        #pragma unroll
        for (int j = 0; j < 8; ++j){
          unsigned short hj = f2bf(e[j]);
          bh[j] = (short)hj;
          se += bf2f(hj);
        }
        if (rw == 1) cs[ct] += se;        // colsum of the bf16-rounded eh (exact match)
        __builtin_amdgcn_s_setprio(1);
        #pragma unroll
        for (int i = 0; i < RH; ++i){
          acc[i][ct] = __builtin_amdgcn_mfma_f32_16x16x32_bf16(ai[i], bh, acc[i][ct], 0, 0, 0);
          acc[i][ct] = __builtin_amdgcn_mfma_f32_16x16x32_bf16(au[i], bh, acc[i][ct], 0, 0, 0);
        }
        __builtin_amdgcn_s_setprio(0);
      }
    }
  }
  // ---- colsum reduce over g groups (lane bits 4,5)
  if (rw == 1){
    #pragma unroll
    for (int ct = 0; ct < 2; ++ct){
      float c = cs[ct];
      c += __shfl_xor(c, 16);
      c += __shfl_xor(c, 32);
      cs[ct] = c;
    }
  }
  // ---- epilogue: bf16 writes; D layout col=lane&15, row=(lane>>4)*4+r
  #pragma unroll
  for (int ct = 0; ct < 2; ++ct){
    unsigned short* rb = raw + (size_t)nh*HS + (size_t)b*RA*NN + m0 + (2*cw + ct)*16 + fc;
    #pragma unroll
    for (int i = 0; i < RH; ++i){
      #pragma unroll
      for (int r = 0; r < 4; ++r){
        int row = rw*(C/2) + i*16 + g*4 + r;
        rb[(size_t)row*NN] = f2bf(acc[i][ct][r]);
      }
    }
    if (rw == 1 && g == 0)
      rb[(size_t)C*NN] = f2bf(cs[ct]);    // only row C is ever read downstream
  }
}

// --------- out = x + relu(bn(wt·(x - raw·csinv) + bt)); raw = bf16 half0 + half1 ---------
template<int C, bool TP>
__global__ __launch_bounds__(256) void attn_post_kernel(const float* __restrict__ x,
      const unsigned short* __restrict__ raw, const float* __restrict__ wt,
      const float* __restrict__ bt, const float* __restrict__ bnp,
      float* __restrict__ out, unsigned short* __restrict__ th,
      unsigned short* __restrict__ tl){
  constexpr int RA = C + 16;
  __shared__ float ds[32][68];
  __shared__ float ws[32][C+4];
  __shared__ float cbs[64];
  const int b = blockIdx.y, m0 = blockIdx.x*64, t = threadIdx.x;
  const size_t HS = (size_t)BB*RA*NN;
  const float* xb = x + (size_t)b*C*NN;
  const unsigned short* rb0 = raw + (size_t)b*RA*NN;
  const unsigned short* rb1 = raw + HS + (size_t)b*RA*NN;
  if (t < 64) cbs[t] = 1.0f / (1e-9f + bf2f(rb0[(size_t)C*NN + m0 + t]) + bf2f(rb1[(size_t)C*NN + m0 + t]));
  const int tr = t >> 4, tc = t & 15;
  constexpr int R = C/16;
  float acc[R][4];
  #pragma unroll
  for (int i = 0; i < R; ++i){ acc[i][0]=acc[i][1]=acc[i][2]=acc[i][3]=0.0f; }
  for (int c0 = 0; c0 < C; c0 += 32){
    __syncthreads();
    #pragma unroll
    for (int i = 0; i < 8; ++i){
      int idx = t + 256*i;
      int m = idx & 63, cl = idx >> 6;
      int cc = c0 + cl;
      float rv = bf2f(rb0[cc*NN + m0 + m]) + bf2f(rb1[cc*NN + m0 + m]);
      ds[cl][m] = xb[cc*NN + m0 + m] - rv * cbs[m];
    }
    #pragma unroll
    for (int i = 0; i < C*32/256; ++i){
      int idx = t + 256*i;
      int cl = idx & 31, o = idx >> 5;
      ws[cl][o] = wt[o*C + c0 + cl];
    }
    __syncthreads();
    #pragma unroll
    for (int k = 0; k < 32; ++k){
      float4 e = *(const float4*)&ds[k][tc*4];
      float a[R];
      #pragma unroll
      for (int q = 0; q < R/4; ++q)
        *(float4*)&a[q*4] = *(const float4*)&ws[k][tr*R + q*4];
      #pragma unroll
      for (int i = 0; i < R; ++i){
        acc[i][0] += a[i]*e.x; acc[i][1] += a[i]*e.y;
        acc[i][2] += a[i]*e.z; acc[i][3] += a[i]*e.w;
      }
    }
  }
  // finalize: acc := x + relu(bn(acc + bt))
  #pragma unroll
  for (int i = 0; i < R; ++i){
    int o = tr*R + i;
    float g = bnp[o], be = bnp[C+o], mn = bnp[2*C+o], vv = bnp[3*C+o];
    float sc = g * rsqrtf(vv + BN_EPS_);
    float sh = be - mn*sc;
    float bv = bt[o];
    #pragma unroll
    for (int j = 0; j < 4; ++j){
      float y = acc[i][j] + bv;
      y = sc*y + sh;
      y = fmaxf(y, 0.0f);
      acc[i][j] = xb[o*NN + m0 + tc*4 + j] + y;
    }
    if (!TP)
      *(float4*)&out[((size_t)b*C + o)*NN + m0 + tc*4] =
          make_float4(acc[i][0], acc[i][1], acc[i][2], acc[i][3]);
  }
  if (TP){
    // LDS transpose (two passes: hi, lo) -> coalesced hT[n][c] global writes
    unsigned short* Ts = (unsigned short*)&ws[0][0];   // 64 rows x 128 shorts = 16 KB
    #pragma unroll
    for (int pass = 0; pass < 2; ++pass){
      __syncthreads();
      #pragma unroll
      for (int q = 0; q < R/2; ++q){
        #pragma unroll
        for (int j = 0; j < 4; ++j){
          int n = tc*4 + j;
          float y0 = acc[2*q][j], y1 = acc[2*q+1][j];
          unsigned short a0 = f2bf(y0), a1 = f2bf(y1);
          unsigned short v0 = pass ? f2bf(y0 - bf2f(a0)) : a0;
          unsigned short v1 = pass ? f2bf(y1 - bf2f(a1)) : a1;
          unsigned off = (unsigned)(n*256) +
              (((unsigned)((tr*R + 2*q)*2)) ^ ((unsigned)((n&7)<<4)));
          *(unsigned*)((char*)Ts + off) = (unsigned)v0 | ((unsigned)v1<<16);
        }
      }
      __syncthreads();
      unsigned short* gout = (pass ? tl : th) + ((size_t)b*NN + m0)*128;
      int n = t >> 2;
      #pragma unroll
      for (int s2 = 0; s2 < 4; ++s2){
        int sl = (t&3)*4 + s2;
        unsigned off = (unsigned)(n*256) + ((unsigned)((sl ^ (n&7)) << 4));
        uint4 v = *(const uint4*)((const char*)Ts + off);
        *(uint4*)(gout + (size_t)n*128 + sl*8) = v;
      }
    }
  }
}

// --------- out = relu(bn(w·x)), dual-write bf16 hi/lo of out for the following attn ---------
template<int CIN, int COUT>
__global__ __launch_bounds__(256) void conv_bn_relu_kernel(const float* __restrict__ x,
      const float* __restrict__ w, const float* __restrict__ bnp, float* __restrict__ out,
      unsigned short* __restrict__ oh, unsigned short* __restrict__ ol){
  constexpr int CH = (CIN < 32) ? CIN : 32;
  __shared__ float xs[CH][68];
  __shared__ float ws[CH][COUT+4];
  const int b = blockIdx.y, m0 = blockIdx.x*64, t = threadIdx.x;
  const float* xb = x + (size_t)b*CIN*NN;
  const int tr = t >> 4, tc = t & 15;
  constexpr int R = COUT/16;
  float acc[R][4];
  #pragma unroll
  for (int i = 0; i < R; ++i){ acc[i][0]=acc[i][1]=acc[i][2]=acc[i][3]=0.0f; }
  for (int c0 = 0; c0 < CIN; c0 += CH){
    __syncthreads();
    for (int idx = t; idx < CH*64; idx += 256){
      int m = idx & 63, cl = idx >> 6;
      xs[cl][m] = xb[(c0+cl)*NN + m0 + m];
    }
    for (int idx = t; idx < CH*COUT; idx += 256){
      int cl = idx % CH, o = idx / CH;
      ws[cl][o] = w[o*CIN + c0 + cl];
    }
    __syncthreads();
    #pragma unroll
    for (int k = 0; k < CH; ++k){
      float4 e = *(const float4*)&xs[k][tc*4];
      float a[R];
      #pragma unroll
      for (int q = 0; q < R/4; ++q)
        *(float4*)&a[q*4] = *(const float4*)&ws[k][tr*R + q*4];
      #pragma unroll
      for (int i = 0; i < R; ++i){
        acc[i][0] += a[i]*e.x; acc[i][1] += a[i]*e.y;
        acc[i][2] += a[i]*e.z; acc[i][3] += a[i]*e.w;
      }
    }
  }
  #pragma unroll
  for (int i = 0; i < R; ++i){
    int o = tr*R + i;
    float g = bnp[o], be = bnp[COUT+o], mn = bnp[2*COUT+o], vv = bnp[3*COUT+o];
    float sc = g * rsqrtf(vv + BN_EPS_);
    float sh = be - mn*sc;
    float4 r;
    float* rp = &r.x;
    #pragma unroll
    for (int j = 0; j < 4; ++j){
      float y = sc*acc[i][j] + sh;
      rp[j] = fmaxf(y, 0.0f);
    }
    size_t base = ((size_t)b*COUT + o)*NN + m0 + tc*4;
    *(float4*)&out[base] = r;
    unsigned short h0=f2bf(r.x), h1=f2bf(r.y), h2=f2bf(r.z), h3=f2bf(r.w);
    uint2 hp, lp;
    hp.x = (unsigned)h0 | ((unsigned)h1<<16);
    hp.y = (unsigned)h2 | ((unsigned)h3<<16);
    lp.x = (unsigned)f2bf(r.x-bf2f(h0)) | ((unsigned)f2bf(r.y-bf2f(h1))<<16);
    lp.y = (unsigned)f2bf(r.z-bf2f(h2)) | ((unsigned)f2bf(r.w-bf2f(h3))<<16);
    *(uint2*)&oh[base] = hp;
    *(uint2*)&ol[base] = lp;
  }
}

// --------- conv5 + pool via MFMA: pooled[b,o] = max_n relu(bn(Σ_c w5[o,c] h[c,n])) ---------
__global__ __launch_bounds__(256, 2) void conv5_mfma_kernel(
      const unsigned short* __restrict__ hTh, const unsigned short* __restrict__ hTl,
      const float* __restrict__ w5, const float* __restrict__ bnp,
      float* __restrict__ pooled){
  __shared__ __align__(16) unsigned short wh[64][128], wl[64][128];  // 32 KB
  __shared__ __align__(16) unsigned short hh[64][128], hl[64][128];  // 32 KB
  const int id = blockIdx.x;                 // id = (b%8) + 8*inner + 512*(b/8)
  const int b  = (id & 7) + ((id >> 9) << 3);
  const int inner = (id >> 3) & 63;
  const int o0 = (inner & 15) * 64;
  const int nb = (inner >> 4) * (NN/4);
  const int t = threadIdx.x;
  const int l = t & 63, w = t >> 6;
  const int rw = w & 1, cw = w >> 1;
  const int fc = l & 15, g = l >> 4;
  const unsigned swr = (unsigned)((fc & 7) << 4);
  #pragma unroll
  for (int i = 0; i < 8; ++i){
    int idx = t + 256*i;                     // 2048 float4
    int row = idx >> 5, c0 = (idx & 31) * 4;
    float4 v = *(const float4*)(w5 + (size_t)(o0 + row)*128 + c0);
    unsigned short h0=f2bf(v.x), h1=f2bf(v.y), h2=f2bf(v.z), h3=f2bf(v.w);
    uint2 hp, lp;
    hp.x = (unsigned)h0 | ((unsigned)h1<<16);
    hp.y = (unsigned)h2 | ((unsigned)h3<<16);
    lp.x = (unsigned)f2bf(v.x-bf2f(h0)) | ((unsigned)f2bf(v.y-bf2f(h1))<<16);
    lp.y = (unsigned)f2bf(v.z-bf2f(h2)) | ((unsigned)f2bf(v.w-bf2f(h3))<<16);
    unsigned off = (unsigned)(row*256) + (((unsigned)(c0*2)) ^ ((unsigned)((row&7)<<4)));
    *(uint2*)((char*)wh + off) = hp;
    *(uint2*)((char*)wl + off) = lp;
  }
  float sc[2][4], sh[2][4];
  #pragma unroll
  for (int i = 0; i < 2; ++i){
    #pragma unroll
    for (int r = 0; r < 4; ++r){
      int o = o0 + rw*32 + i*16 + g*4 + r;
      float gg = bnp[o], be = bnp[1024+o], mn = bnp[2048+o], vv = bnp[3072+o];
      sc[i][r] = gg * rsqrtf(vv + BN_EPS_);
      sh[i][r] = be - mn*sc[i][r];
    }
  }
  float vmax[2][4] = {{0.f,0.f,0.f,0.f},{0.f,0.f,0.f,0.f}};
  const unsigned short* hb = hTh + (size_t)b*NN*128;
  const unsigned short* lb = hTl + (size_t)b*NN*128;
  for (int nt = 0; nt < (NN/4)/64; ++nt){
    const int n0 = nb + nt*64;
    __syncthreads();
    #pragma unroll
    for (int i = 0; i < 4; ++i){
      int idx = t + 256*i;                  // 1024 uint4 per buffer
      int row = idx >> 4, sl = idx & 15;
      unsigned off = (unsigned)(row*256) + ((unsigned)((sl << 4) ^ ((row&7)<<4)));
      *(uint4*)((char*)hh + off) = *(const uint4*)(hb + (size_t)(n0+row)*128 + sl*8);
      *(uint4*)((char*)hl + off) = *(const uint4*)(lb + (size_t)(n0+row)*128 + sl*8);
    }
    __syncthreads();
    f32x4 acc[2][2];
    #pragma unroll
    for (int i = 0; i < 2; ++i){ acc[i][0] = (f32x4){0.f,0.f,0.f,0.f}; acc[i][1] = (f32x4){0.f,0.f,0.f,0.f}; }
    #pragma unroll
    for (int kk = 0; kk < 4; ++kk){
      unsigned ko = ((unsigned)((kk*32 + g*8)*2)) ^ swr;
      short8v aih[2], ail[2], bih[2], bil[2];
      #pragma unroll
      for (int i = 0; i < 2; ++i){
        unsigned aoff = (unsigned)((rw*32 + i*16 + fc)*256) + ko;
        aih[i] = *(const short8v*)((const char*)wh + aoff);
        ail[i] = *(const short8v*)((const char*)wl + aoff);
      }
      #pragma unroll
      for (int ct = 0; ct < 2; ++ct){
        unsigned boff = (unsigned)((cw*32 + ct*16 + fc)*256) + ko;
        bih[ct] = *(const short8v*)((const char*)hh + boff);
        bil[ct] = *(const short8v*)((const char*)hl + boff);
      }
      #pragma unroll
      for (int i = 0; i < 2; ++i){
        #pragma unroll
        for (int ct = 0; ct < 2; ++ct){
          acc[i][ct] = __builtin_amdgcn_mfma_f32_16x16x32_bf16(aih[i], bih[ct], acc[i][ct], 0, 0, 0);
          acc[i][ct] = __builtin_amdgcn_mfma_f32_16x16x32_bf16(aih[i], bil[ct], acc[i][ct], 0, 0, 0);
          acc[i][ct] = __builtin_amdgcn_mfma_f32_16x16x32_bf16(ail[i], bih[ct], acc[i][ct], 0, 0, 0);
        }
      }
    }
    #pragma unroll
    for (int i = 0; i < 2; ++i){
      #pragma unroll
      for (int ct = 0; ct < 2; ++ct){
        #pragma unroll
        for (int r = 0; r < 4; ++r){
          float y = sc[i][r]*acc[i][ct][r] + sh[i][r];
          y = fmaxf(y, 0.0f);
          vmax[i][r] = fmaxf(vmax[i][r], y);
        }
      }
    }
  }
  #pragma unroll
  for (int i = 0; i < 2; ++i){
    #pragma unroll
    for (int r = 0; r < 4; ++r){
      float v = vmax[i][r];
      v = fmaxf(v, __shfl_xor(v, 1));
      v = fmaxf(v, __shfl_xor(v, 2));
      v = fmaxf(v, __shfl_xor(v, 4));
      v = fmaxf(v, __shfl_xor(v, 8));
      if (fc == 0)
        atomicMax((unsigned int*)&pooled[b*1024 + o0 + rw*32 + i*16 + g*4 + r],
                  __float_as_uint(v));
    }
  }
}

// --------- lin1 + bn6 + relu ---------
__global__ void lin1_kernel(const float* __restrict__ pooled, const float* __restrict__ w,
      const float* __restrict__ bnp, float* __restrict__ out1){
  int tid = blockIdx.x*256 + threadIdx.x;
  int b = tid >> 9, j = tid & 511;
  const float4* p4 = (const float4*)(pooled + b*1024);
  const float4* w4 = (const float4*)(w + j*1024);
  float sum = 0.0f;
  for (int e = 0; e < 256; ++e){
    float4 a = p4[e], c = w4[e];
    sum += a.x*c.x + a.y*c.y + a.z*c.z + a.w*c.w;
  }
  float g = bnp[j], be = bnp[512+j], mn = bnp[2*512+j], vv = bnp[3*512+j];
  float s = g * rsqrtf(vv + BN_EPS_);
  float y = s*sum + (be - mn*s);
  out1[b*512 + j] = fmaxf(y, 0.0f);
}

// --------- lin2 ---------
__global__ void lin2_kernel(const float* __restrict__ h, const float* __restrict__ w,
      const float* __restrict__ bias, float* __restrict__ out){
  int tid = blockIdx.x*64 + threadIdx.x;
  if (tid >= 640) return;
  int b = tid / 40, k = tid % 40;
  const float4* h4 = (const float4*)(h + b*512);
  const float4* w4 = (const float4*)(w + k*512);
  float sum = 0.0f;
  for (int e = 0; e < 128; ++e){
    float4 a = h4[e], c = w4[e];
    sum += a.x*c.x + a.y*c.y + a.z*c.z + a.w*c.w;
  }
  out[tid] = sum + bias[k];
}

extern "C" void kernel_launch(void* const* d_in, const int* in_sizes, int n_in,
                              void* d_out, int out_size, void* d_ws, size_t ws_size,
                              hipStream_t stream){
  (void)in_sizes; (void)n_in; (void)out_size; (void)ws_size;
  const float* x     = (const float*)d_in[0];
  const float* w1    = (const float*)d_in[1];
  const float* w2    = (const float*)d_in[2];
  const float* w3    = (const float*)d_in[3];
  const float* w4    = (const float*)d_in[4];
  const float* w5    = (const float*)d_in[5];
  const float* bn1   = (const float*)d_in[6];
  const float* bn2   = (const float*)d_in[7];
  const float* bn3   = (const float*)d_in[8];
  const float* bn4   = (const float*)d_in[9];
  const float* bn5   = (const float*)d_in[10];
  const float* da_wqk[4] = {(const float*)d_in[11], (const float*)d_in[15], (const float*)d_in[19], (const float*)d_in[23]};
  const float* da_wt[4]  = {(const float*)d_in[12], (const float*)d_in[16], (const float*)d_in[20], (const float*)d_in[24]};
  const float* da_bt[4]  = {(const float*)d_in[13], (const float*)d_in[17], (const float*)d_in[21], (const float*)d_in[25]};
  const float* da_bn[4]  = {(const float*)d_in[14], (const float*)d_in[18], (const float*)d_in[22], (const float*)d_in[26]};
  const float* lin1_w = (const float*)d_in[27];
  const float* bn6    = (const float*)d_in[28];
  const float* lin2_w = (const float*)d_in[29];
  const float* lin2_b = (const float*)d_in[30];

  float* ws = (float*)d_ws;
  float* maxval = ws;                   // 1 float (padded to 64)
  float* dens   = ws + 64;
  float* zinv4  = dens + BB*NN;                     // 4 layers' zinv
  float* hA     = zinv4 + 4*(size_t)BB*NN;
  float* hB     = hA  + (size_t)BB*64*NN;
  float* h4A    = hB  + (size_t)BB*64*NN;
  unsigned short* raw = (unsigned short*)(h4A + (size_t)BB*128*NN);  // 2 bf16 halves, RA=144
  float* pooled = (float*)raw + (size_t)BB*144*NN;
  float* l1o    = pooled + BB*1024;
  float* blockmax = l1o + BB*512;               // 4096 floats
  unsigned short* Ah = (unsigned short*)(blockmax + 4096);   // BB*128*NN bf16
  unsigned short* Al = Ah + (size_t)BB*128*NN;
  float* h4B    = hA;   // (unused in TP mode; kept for signature)

  density7_kernel<<<dim3(NN/DG, BB), 512, 0, stream>>>(x, dens, blockmax);
  finalize_max_kernel<<<dim3(1), 256, 0, stream>>>(blockmax, maxval);
  zrow4_kernel<<<dim3(32,BB), 256, 0, stream>>>(dens, maxval,
      da_wqk[0], da_wqk[1], da_wqk[2], da_wqk[3], zinv4);

  conv_bn_relu_kernel<3,64><<<dim3(32,BB),256,0,stream>>>(x, w1, bn1, hA, Ah, Al);

  // attn1: hA -> hB
  attn_mfma_kernel<64><<<dim3(1024),256,0,stream>>>(Ah, Al, dens, zinv4, da_wqk[0], 16, maxval, raw);
  attn_post_kernel<64,false><<<dim3(32,BB),256,0,stream>>>(hA, raw, da_wt[0], da_bt[0], da_bn[0], hB, nullptr, nullptr);

  conv_bn_relu_kernel<64,64><<<dim3(32,BB),256,0,stream>>>(hB, w2, bn2, hA, Ah, Al);

  // attn2: hA -> hB
  attn_mfma_kernel<64><<<dim3(1024),256,0,stream>>>(Ah, Al, dens, zinv4 + (size_t)BB*NN, da_wqk[1], 16, maxval, raw);
  attn_post_kernel<64,false><<<dim3(32,BB),256,0,stream>>>(hA, raw, da_wt[1], da_bt[1], da_bn[1], hB, nullptr, nullptr);

  conv_bn_relu_kernel<64,64><<<dim3(32,BB),256,0,stream>>>(hB, w3, bn3, hA, Ah, Al);

  // attn3: hA -> hB
  attn_mfma_kernel<64><<<dim3(1024),256,0,stream>>>(Ah, Al, dens, zinv4 + 2*(size_t)BB*NN, da_wqk[2], 16, maxval, raw);
  attn_post_kernel<64,false><<<dim3(32,BB),256,0,stream>>>(hA, raw, da_wt[2], da_bt[2], da_bn[2], hB, nullptr, nullptr);

  conv_bn_relu_kernel<64,128><<<dim3(32,BB),256,0,stream>>>(hB, w4, bn4, h4A, Ah, Al);

  // attn4 (C=128): h4A -> hT (transposed bf16 hi/lo, reusing Ah/Al after attn4_mfma)
  attn_mfma_kernel<128><<<dim3(1024),256,0,stream>>>(Ah, Al, dens, zinv4 + 3*(size_t)BB*NN, da_wqk[3], 32, maxval, raw);
  attn_post_kernel<128,true><<<dim3(32,BB),256,0,stream>>>(h4A, raw, da_wt[3], da_bt[3], da_bn[3], h4B, Ah, Al);

  hipMemsetAsync(pooled, 0, BB*1024*sizeof(float), stream);
  conv5_mfma_kernel<<<dim3(1024),256,0,stream>>>(Ah, Al, w5, bn5, pooled);
  lin1_kernel<<<dim3(32),256,0,stream>>>(pooled, lin1_w, bn6, l1o);
  lin2_kernel<<<dim3(10),64,0,stream>>>(l1o, lin2_w, lin2_b, (float*)d_out);
}

// Round 19
// 498.185 us; speedup vs baseline: 1.0846x; 1.0846x over previous
//
#include <hip/hip_runtime.h>
#include <math.h>

#define BB 16
#define NN 2048
#define BN_EPS_ 1e-5f

typedef __attribute__((ext_vector_type(8))) short short8v;   // 8 bf16 (4 VGPRs)
typedef __attribute__((ext_vector_type(4))) float f32x4;

__device__ __forceinline__ unsigned short f2bf(float x){
  unsigned u = __float_as_uint(x);
  u += 0x7fffu + ((u >> 16) & 1u);          // round-to-nearest-even
  return (unsigned short)(u >> 16);
}
__device__ __forceinline__ float bf2f(unsigned short h){
  return __uint_as_float(((unsigned)h) << 16);
}

// ---------------- density v7: 512 threads, wave-per-row phases, inline point-normalize ----------------
#define DG 8
__global__ __launch_bounds__(512) void density7_kernel(const float* __restrict__ x,
        float* __restrict__ inv, float* __restrict__ blockmax){
  __shared__ float us0[NN], us1[NN], us2[NN];      // 24 KiB
  __shared__ unsigned int hist[DG][256];           // 8 KiB
  __shared__ float buf[DG][128];                   // 4 KiB
  __shared__ unsigned int bufcnt[DG];
  __shared__ unsigned int bB[DG], bC0[DG];
  __shared__ float partial[DG][8];
  __shared__ float rowiv[DG];
  const int b = blockIdx.y;
  const float* xb = x + (size_t)b*3*NN;
  const int t = threadIdx.x;                       // 0..511
  {
    float4 v0 = ((const float4*)xb)[t];
    float4 v1 = ((const float4*)(xb + NN))[t];
    float4 v2 = ((const float4*)(xb + 2*NN))[t];
    float4 rr;
    rr.x = rsqrtf(v0.x*v0.x + v1.x*v1.x + v2.x*v2.x);
    rr.y = rsqrtf(v0.y*v0.y + v1.y*v1.y + v2.y*v2.y);
    rr.z = rsqrtf(v0.z*v0.z + v1.z*v1.z + v2.z*v2.z);
    rr.w = rsqrtf(v0.w*v0.w + v1.w*v1.w + v2.w*v2.w);
    v0.x*=rr.x; v0.y*=rr.y; v0.z*=rr.z; v0.w*=rr.w;
    v1.x*=rr.x; v1.y*=rr.y; v1.z*=rr.z; v1.w*=rr.w;
    v2.x*=rr.x; v2.y*=rr.y; v2.z*=rr.z; v2.w*=rr.w;
    ((float4*)us0)[t] = v0; ((float4*)us1)[t] = v1; ((float4*)us2)[t] = v2;
  }
  #pragma unroll
  for (int i = 0; i < 4; ++i) ((unsigned*)hist)[t + 512*i] = 0u;
  if (t < DG) bufcnt[t] = 0u;
  __syncthreads();
  float m0[4], m1[4], m2[4];
  #pragma unroll
  for (int i = 0; i < 4; ++i){
    int c = t + 512*i;
    m0[i] = us0[c]; m1[i] = us1[c]; m2[i] = us2[c];
  }
  const int r0 = blockIdx.x * DG;
  float dd[DG][4]; unsigned qp[DG];
  #pragma unroll
  for (int j = 0; j < DG; ++j){
    float ru0 = us0[r0+j], ru1 = us1[r0+j], ru2 = us2[r0+j];
    unsigned q0 = 0u;
    #pragma unroll
    for (int i = 0; i < 4; ++i){
      float d = 1.0f - (ru0*m0[i] + ru1*m1[i] + ru2*m2[i]);
      dd[j][i] = d;
      int q = (int)(d * 128.0f);
      q = q < 0 ? 0 : (q > 255 ? 255 : q);
      q0 |= (unsigned)q << (8*i);
      atomicAdd(&hist[j][q], 1u);
    }
    qp[j] = q0;
  }
  __syncthreads();

  const int wave = t >> 6, lane = t & 63;
  {
    const int j = wave;
    uint4 cc = *(const uint4*)&hist[j][lane*4];
    unsigned tl = cc.x + cc.y + cc.z + cc.w;
    unsigned inc = tl;
    #pragma unroll
    for (int off = 1; off < 64; off <<= 1){
      unsigned o = __shfl_up(inc, off);
      if (lane >= off) inc += o;
    }
    unsigned base = inc - tl;
    if (base < 32u && base + tl >= 32u){
      unsigned cum = base;
      if (cum < 32u && cum + cc.x >= 32u){ bB[j] = lane*4 + 0; bC0[j] = cum; } cum += cc.x;
      if (cum < 32u && cum + cc.y >= 32u){ bB[j] = lane*4 + 1; bC0[j] = cum; } cum += cc.y;
      if (cum < 32u && cum + cc.z >= 32u){ bB[j] = lane*4 + 2; bC0[j] = cum; } cum += cc.z;
      if (cum < 32u && cum + cc.w >= 32u){ bB[j] = lane*4 + 3; bC0[j] = cum; } cum += cc.w;
    }
  }
  __syncthreads();

  #pragma unroll
  for (int j = 0; j < DG; ++j){
    const int B = (int)bB[j];
    float s = 0.0f;
    #pragma unroll
    for (int i = 0; i < 4; ++i){
      float d = dd[j][i];
      int q = (int)((qp[j] >> (8*i)) & 255u);
      if (q < B) s += d;
      else if (q == B){
        unsigned slot = atomicAdd(&bufcnt[j], 1u);
        if (slot < 128u) buf[j][slot] = d;
      }
    }
    #pragma unroll
    for (int off = 32; off > 0; off >>= 1) s += __shfl_xor(s, off);
    if (lane == 0) partial[j][wave] = s;
  }
  __syncthreads();

  {
    const int j = wave;
    float total = 0.0f;
    #pragma unroll
    for (int wv = 0; wv < 8; ++wv) total += partial[j][wv];
    int cnt = (int)bufcnt[j]; if (cnt > 128) cnt = 128;
    const int rr = 32 - (int)bC0[j];
    float v1 = (lane      < cnt) ? buf[j][lane]      : 0.0f;
    float v2 = (lane + 64 < cnt) ? buf[j][lane + 64] : 0.0f;
    int rk1 = 0, rk2 = 0;
    for (int k = 0; k < cnt; ++k){
      float vk = buf[j][k];
      rk1 += ((vk < v1) || (vk == v1 && k < lane)) ? 1 : 0;
      rk2 += ((vk < v2) || (vk == v2 && k < lane + 64)) ? 1 : 0;
    }
    float contrib = ((lane      < cnt) && (rk1 < rr)) ? v1 : 0.0f;
    contrib      += ((lane + 64 < cnt) && (rk2 < rr)) ? v2 : 0.0f;
    #pragma unroll
    for (int off = 32; off > 0; off >>= 1) contrib += __shfl_xor(contrib, off);
    total += contrib;
    if (lane == 0){
      float iv = 32.0f / total;
      inv[b*NN + r0 + j] = iv;
      rowiv[j] = iv;
    }
  }
  __syncthreads();
  if (t == 0){
    float m = rowiv[0];
    #pragma unroll
    for (int j = 1; j < DG; ++j) m = fmaxf(m, rowiv[j]);
    blockmax[blockIdx.y * gridDim.x + blockIdx.x] = m;
  }
}

__global__ __launch_bounds__(256) void finalize_max_kernel(const float* __restrict__ blockmax,
        float* __restrict__ maxout){
  __shared__ float pw[4];
  const int t = threadIdx.x;
  float m = 0.0f;
  #pragma unroll
  for (int i = 0; i < 16; ++i) m = fmaxf(m, blockmax[t + 256*i]);
  #pragma unroll
  for (int off = 32; off > 0; off >>= 1) m = fmaxf(m, __shfl_xor(m, off));
  if ((t & 63) == 0) pw[t >> 6] = m;
  __syncthreads();
  if (t == 0) *maxout = fmaxf(fmaxf(pw[0], pw[1]), fmaxf(pw[2], pw[3]));
}

// --------- Zinv for ALL 4 layers: out[l][b][r] = 1/Σ_m exp(s_l·d_r·d_m), s_l incl. 1/mx² ---------
__global__ __launch_bounds__(256) void zrow4_kernel(const float* __restrict__ dens,
      const float* __restrict__ maxval,
      const float* __restrict__ w0, const float* __restrict__ w1,
      const float* __restrict__ w2, const float* __restrict__ w3,
      float* __restrict__ out){
  __shared__ float ds[NN];
  const int b = blockIdx.y, t = threadIdx.x;
  float mx = *maxval;
  float r2 = 1.0f / (mx*mx);
  float s0=0.f, s1=0.f, s2=0.f, s3=0.f;
  for (int k = 0; k < 16; ++k){ float w = w0[k]; s0 += w*w; }
  for (int k = 0; k < 16; ++k){ float w = w1[k]; s1 += w*w; }
  for (int k = 0; k < 16; ++k){ float w = w2[k]; s2 += w*w; }
  for (int k = 0; k < 32; ++k){ float w = w3[k]; s3 += w*w; }
  s0 *= r2; s1 *= r2; s2 *= r2; s3 *= r2;
  #pragma unroll
  for (int i = 0; i < NN/256; ++i) ds[t + 256*i] = dens[b*NN + t + 256*i];
  __syncthreads();
  const int wave = t >> 6, lane = t & 63;
  const int RPB = NN / gridDim.x;
  const int r0 = blockIdx.x * RPB;
  for (int r = r0 + wave; r < r0 + RPB; r += 4){
    float dr = ds[r];
    float a0 = s0*dr, a1 = s1*dr, a2 = s2*dr, a3 = s3*dr;
    float q0=0.f, q1=0.f, q2=0.f, q3=0.f;
    #pragma unroll
    for (int i = 0; i < NN/64; ++i){
      float dm = ds[lane + 64*i];
      q0 += __expf(a0*dm); q1 += __expf(a1*dm);
      q2 += __expf(a2*dm); q3 += __expf(a3*dm);
    }
    #pragma unroll
    for (int off = 32; off > 0; off >>= 1){
      q0 += __shfl_xor(q0, off); q1 += __shfl_xor(q1, off);
      q2 += __shfl_xor(q2, off); q3 += __shfl_xor(q3, off);
    }
    if (lane == 0){
      out[0*(size_t)BB*NN + b*NN + r] = 1.0f/q0;
      out[1*(size_t)BB*NN + b*NN + r] = 1.0f/q1;
      out[2*(size_t)BB*NN + b*NN + r] = 1.0f/q2;
      out[3*(size_t)BB*NN + b*NN + r] = 1.0f/q3;
    }
  }
}

// --------- MFMA attention GEMM v8 (E hi-only, n-split 2-way, bf16 raw, mx folded into s) ---------
template<int C>
__global__ __launch_bounds__(256, 2) void attn_mfma_kernel(const unsigned short* __restrict__ Ah,
      const unsigned short* __restrict__ Al, const float* __restrict__ dens,
      const float* __restrict__ zinv, const float* __restrict__ wqk, int K,
      const float* __restrict__ maxval, unsigned short* __restrict__ raw){
  constexpr int RA = C + 16;          // raw rows (colsum row at C)
  constexpr int RH = C / 32;          // A row-tiles per wave
  __shared__ __align__(16) unsigned short ah[C][64], al[C][64];   // 32 KB (C=128)
  __shared__ __align__(16) unsigned short eh[64][64];             // 8 KB
  const int id = blockIdx.x;
  const int b  = (id & 7) + ((id >> 9) << 3);
  const int inner = (id >> 3) & 63;
  const int m0 = (inner & 31) * 64;
  const int nh = inner >> 5;
  const size_t HS = (size_t)BB*RA*NN;            // half-buffer stride (ushorts)
  const int t = threadIdx.x;
  float s = 0.0f;
  for (int k = 0; k < K; ++k){ float w = wqk[k]; s += w*w; }
  { float mx = *maxval; s = s / (mx*mx); }
  const float* db = dens + b*NN;
  const float* zb = zinv + b*NN;
  const unsigned short* Abh = Ah + (size_t)b*C*NN;
  const unsigned short* Abl = Al + (size_t)b*C*NN;
  const int ej = t >> 2, ekq = (t & 3) * 16;       // E-gen: row (m) / k-quarter
  const float dmj = s * db[m0 + ej];
  const unsigned swe = (unsigned)((ej & 7) << 4);
  const int l = t & 63, w = t >> 6;
  const int rw = w & 1, cw = w >> 1;               // 2x2 wave quadrant
  const int fc = l & 15, g = l >> 4;
  const unsigned swr = (unsigned)((fc & 7) << 4);
  short8v ones8, zero8;
  #pragma unroll
  for (int q = 0; q < 8; ++q){ ones8[q] = (short)0x3F80; zero8[q] = 0; }
  f32x4 acc[RH][2], cs[2];
  #pragma unroll
  for (int i = 0; i < RH; ++i){ acc[i][0] = (f32x4){0.f,0.f,0.f,0.f}; acc[i][1] = (f32x4){0.f,0.f,0.f,0.f}; }
  cs[0] = (f32x4){0.f,0.f,0.f,0.f}; cs[1] = (f32x4){0.f,0.f,0.f,0.f};

  for (int n0 = nh*(NN/2); n0 < (nh+1)*(NN/2); n0 += 64){
    __syncthreads();
    // ---- stage A: coalesced uint4 copy from precomputed global hi/lo, swizzled write
    #pragma unroll
    for (int i = 0; i < C*8/256; ++i){
      int idx = t + 256*i;
      int row = idx >> 3, c8 = (idx & 7) * 8;
      unsigned off = (unsigned)(row*128) + (((unsigned)(c8*2)) ^ ((unsigned)((row&7)<<4)));
      *(uint4*)((char*)ah + off) = *(const uint4*)(Abh + (size_t)row*NN + n0 + c8);
      *(uint4*)((char*)al + off) = *(const uint4*)(Abl + (size_t)row*NN + n0 + c8);
    }
    // ---- stage E (hi only): eh[j][k] = bf16(zinv_k·exp(s·d[n0+k]·d[m0+j])), 16 k/thread
    {
      unsigned hp[8];
      #pragma unroll
      for (int u = 0; u < 4; ++u){
        float4 dn = *(const float4*)(db + n0 + ekq + u*4);
        float4 zv = *(const float4*)(zb + n0 + ekq + u*4);
        float e0 = zv.x*__expf(dn.x*dmj), e1 = zv.y*__expf(dn.y*dmj);
        float e2 = zv.z*__expf(dn.z*dmj), e3 = zv.w*__expf(dn.w*dmj);
        hp[u*2+0] = (unsigned)f2bf(e0) | ((unsigned)f2bf(e1)<<16);
        hp[u*2+1] = (unsigned)f2bf(e2) | ((unsigned)f2bf(e3)<<16);
      }
      unsigned row = (unsigned)(ej*128);
      unsigned o1 = row + (((unsigned)(ekq*2))      ^ swe);
      unsigned o2 = row + (((unsigned)(ekq*2 + 16)) ^ swe);
      *(uint4*)((char*)eh + o1) = make_uint4(hp[0],hp[1],hp[2],hp[3]);
      *(uint4*)((char*)eh + o2) = make_uint4(hp[4],hp[5],hp[6],hp[7]);
    }
    __syncthreads();
    // ---- MFMA: D(16x16) += A(16x32)·B(32x16); 2-term (A hi+lo) x E-hi
    #pragma unroll
    for (int kk = 0; kk < 2; ++kk){
      unsigned ko = ((unsigned)((kk*32 + g*8)*2)) ^ swr;
      short8v bh[2], ai[RH], au[RH];
      #pragma unroll
      for (int ct = 0; ct < 2; ++ct){
        unsigned eoff = (unsigned)(((2*cw + ct)*16 + fc)*128) + ko;
        bh[ct] = *(const short8v*)((const char*)eh + eoff);
      }
      #pragma unroll
      for (int i = 0; i < RH; ++i){
        unsigned aoff = (unsigned)((rw*(C/2) + i*16 + fc)*128) + ko;
        ai[i] = *(const short8v*)((const char*)ah + aoff);
        au[i] = *(const short8v*)((const char*)al + aoff);
      }
      __builtin_amdgcn_s_setprio(1);
      #pragma unroll
      for (int i = 0; i < RH; ++i){
        #pragma unroll
        for (int ct = 0; ct < 2; ++ct){
          acc[i][ct] = __builtin_amdgcn_mfma_f32_16x16x32_bf16(ai[i], bh[ct], acc[i][ct], 0, 0, 0);
          acc[i][ct] = __builtin_amdgcn_mfma_f32_16x16x32_bf16(au[i], bh[ct], acc[i][ct], 0, 0, 0);
        }
      }
      if (rw == 1){
        short8v ac = (fc == 0) ? ones8 : zero8;
        #pragma unroll
        for (int ct = 0; ct < 2; ++ct)
          cs[ct] = __builtin_amdgcn_mfma_f32_16x16x32_bf16(ac, bh[ct], cs[ct], 0, 0, 0);
      }
      __builtin_amdgcn_s_setprio(0);
    }
  }
  // ---- epilogue: bf16 writes; D layout col=lane&15, row=(lane>>4)*4+r
  #pragma unroll
  for (int ct = 0; ct < 2; ++ct){
    unsigned short* rb = raw + (size_t)nh*HS + (size_t)b*RA*NN + m0 + (2*cw + ct)*16 + fc;
    #pragma unroll
    for (int i = 0; i < RH; ++i){
      #pragma unroll
      for (int r = 0; r < 4; ++r){
        int row = rw*(C/2) + i*16 + g*4 + r;
        rb[(size_t)row*NN] = f2bf(acc[i][ct][r]);
      }
    }
    if (rw == 1){
      #pragma unroll
      for (int r = 0; r < 4; ++r){
        int row = C + g*4 + r;
        rb[(size_t)row*NN] = f2bf(cs[ct][r]);
      }
    }
  }
}

// --------- out = x + relu(bn(wt·(x - raw·csinv) + bt)); raw = bf16 half0 + half1 ---------
template<int C, bool TP>
__global__ __launch_bounds__(256) void attn_post_kernel(const float* __restrict__ x,
      const unsigned short* __restrict__ raw, const float* __restrict__ wt,
      const float* __restrict__ bt, const float* __restrict__ bnp,
      float* __restrict__ out, unsigned short* __restrict__ th,
      unsigned short* __restrict__ tl){
  constexpr int RA = C + 16;
  __shared__ float ds[32][68];
  __shared__ float ws[32][C+4];
  __shared__ float cbs[64];
  const int b = blockIdx.y, m0 = blockIdx.x*64, t = threadIdx.x;
  const size_t HS = (size_t)BB*RA*NN;
  const float* xb = x + (size_t)b*C*NN;
  const unsigned short* rb0 = raw + (size_t)b*RA*NN;
  const unsigned short* rb1 = raw + HS + (size_t)b*RA*NN;
  if (t < 64) cbs[t] = 1.0f / (1e-9f + bf2f(rb0[(size_t)C*NN + m0 + t]) + bf2f(rb1[(size_t)C*NN + m0 + t]));
  const int tr = t >> 4, tc = t & 15;
  constexpr int R = C/16;
  float acc[R][4];
  #pragma unroll
  for (int i = 0; i < R; ++i){ acc[i][0]=acc[i][1]=acc[i][2]=acc[i][3]=0.0f; }
  for (int c0 = 0; c0 < C; c0 += 32){
    __syncthreads();
    #pragma unroll
    for (int i = 0; i < 8; ++i){
      int idx = t + 256*i;
      int m = idx & 63, cl = idx >> 6;
      int cc = c0 + cl;
      float rv = bf2f(rb0[cc*NN + m0 + m]) + bf2f(rb1[cc*NN + m0 + m]);
      ds[cl][m] = xb[cc*NN + m0 + m] - rv * cbs[m];
    }
    #pragma unroll
    for (int i = 0; i < C*32/256; ++i){
      int idx = t + 256*i;
      int cl = idx & 31, o = idx >> 5;
      ws[cl][o] = wt[o*C + c0 + cl];
    }
    __syncthreads();
    #pragma unroll
    for (int k = 0; k < 32; ++k){
      float4 e = *(const float4*)&ds[k][tc*4];
      float a[R];
      #pragma unroll
      for (int q = 0; q < R/4; ++q)
        *(float4*)&a[q*4] = *(const float4*)&ws[k][tr*R + q*4];
      #pragma unroll
      for (int i = 0; i < R; ++i){
        acc[i][0] += a[i]*e.x; acc[i][1] += a[i]*e.y;
        acc[i][2] += a[i]*e.z; acc[i][3] += a[i]*e.w;
      }
    }
  }
  // finalize: acc := x + relu(bn(acc + bt))
  #pragma unroll
  for (int i = 0; i < R; ++i){
    int o = tr*R + i;
    float g = bnp[o], be = bnp[C+o], mn = bnp[2*C+o], vv = bnp[3*C+o];
    float sc = g * rsqrtf(vv + BN_EPS_);
    float sh = be - mn*sc;
    float bv = bt[o];
    #pragma unroll
    for (int j = 0; j < 4; ++j){
      float y = acc[i][j] + bv;
      y = sc*y + sh;
      y = fmaxf(y, 0.0f);
      acc[i][j] = xb[o*NN + m0 + tc*4 + j] + y;
    }
    if (!TP)
      *(float4*)&out[((size_t)b*C + o)*NN + m0 + tc*4] =
          make_float4(acc[i][0], acc[i][1], acc[i][2], acc[i][3]);
  }
  if (TP){
    // LDS transpose (two passes: hi, lo) -> coalesced hT[n][c] global writes
    unsigned short* Ts = (unsigned short*)&ws[0][0];   // 64 rows x 128 shorts = 16 KB
    #pragma unroll
    for (int pass = 0; pass < 2; ++pass){
      __syncthreads();
      #pragma unroll
      for (int q = 0; q < R/2; ++q){
        #pragma unroll
        for (int j = 0; j < 4; ++j){
          int n = tc*4 + j;
          float y0 = acc[2*q][j], y1 = acc[2*q+1][j];
          unsigned short a0 = f2bf(y0), a1 = f2bf(y1);
          unsigned short v0 = pass ? f2bf(y0 - bf2f(a0)) : a0;
          unsigned short v1 = pass ? f2bf(y1 - bf2f(a1)) : a1;
          unsigned off = (unsigned)(n*256) +
              (((unsigned)((tr*R + 2*q)*2)) ^ ((unsigned)((n&7)<<4)));
          *(unsigned*)((char*)Ts + off) = (unsigned)v0 | ((unsigned)v1<<16);
        }
      }
      __syncthreads();
      unsigned short* gout = (pass ? tl : th) + ((size_t)b*NN + m0)*128;
      int n = t >> 2;
      #pragma unroll
      for (int s2 = 0; s2 < 4; ++s2){
        int sl = (t&3)*4 + s2;
        unsigned off = (unsigned)(n*256) + ((unsigned)((sl ^ (n&7)) << 4));
        uint4 v = *(const uint4*)((const char*)Ts + off);
        *(uint4*)(gout + (size_t)n*128 + sl*8) = v;
      }
    }
  }
}

// --------- out = relu(bn(w·x)), dual-write bf16 hi/lo of out for the following attn ---------
template<int CIN, int COUT>
__global__ __launch_bounds__(256) void conv_bn_relu_kernel(const float* __restrict__ x,
      const float* __restrict__ w, const float* __restrict__ bnp, float* __restrict__ out,
      unsigned short* __restrict__ oh, unsigned short* __restrict__ ol){
  constexpr int CH = (CIN < 32) ? CIN : 32;
  __shared__ float xs[CH][68];
  __shared__ float ws[CH][COUT+4];
  const int b = blockIdx.y, m0 = blockIdx.x*64, t = threadIdx.x;
  const float* xb = x + (size_t)b*CIN*NN;
  const int tr = t >> 4, tc = t & 15;
  constexpr int R = COUT/16;
  float acc[R][4];
  #pragma unroll
  for (int i = 0; i < R; ++i){ acc[i][0]=acc[i][1]=acc[i][2]=acc[i][3]=0.0f; }
  for (int c0 = 0; c0 < CIN; c0 += CH){
    __syncthreads();
    for (int idx = t; idx < CH*64; idx += 256){
      int m = idx & 63, cl = idx >> 6;
      xs[cl][m] = xb[(c0+cl)*NN + m0 + m];
    }
    for (int idx = t; idx < CH*COUT; idx += 256){
      int cl = idx % CH, o = idx / CH;
      ws[cl][o] = w[o*CIN + c0 + cl];
    }
    __syncthreads();
    #pragma unroll
    for (int k = 0; k < CH; ++k){
      float4 e = *(const float4*)&xs[k][tc*4];
      float a[R];
      #pragma unroll
      for (int q = 0; q < R/4; ++q)
        *(float4*)&a[q*4] = *(const float4*)&ws[k][tr*R + q*4];
      #pragma unroll
      for (int i = 0; i < R; ++i){
        acc[i][0] += a[i]*e.x; acc[i][1] += a[i]*e.y;
        acc[i][2] += a[i]*e.z; acc[i][3] += a[i]*e.w;
      }
    }
  }
  #pragma unroll
  for (int i = 0; i < R; ++i){
    int o = tr*R + i;
    float g = bnp[o], be = bnp[COUT+o], mn = bnp[2*COUT+o], vv = bnp[3*COUT+o];
    float sc = g * rsqrtf(vv + BN_EPS_);
    float sh = be - mn*sc;
    float4 r;
    float* rp = &r.x;
    #pragma unroll
    for (int j = 0; j < 4; ++j){
      float y = sc*acc[i][j] + sh;
      rp[j] = fmaxf(y, 0.0f);
    }
    size_t base = ((size_t)b*COUT + o)*NN + m0 + tc*4;
    *(float4*)&out[base] = r;
    unsigned short h0=f2bf(r.x), h1=f2bf(r.y), h2=f2bf(r.z), h3=f2bf(r.w);
    uint2 hp, lp;
    hp.x = (unsigned)h0 | ((unsigned)h1<<16);
    hp.y = (unsigned)h2 | ((unsigned)h3<<16);
    lp.x = (unsigned)f2bf(r.x-bf2f(h0)) | ((unsigned)f2bf(r.y-bf2f(h1))<<16);
    lp.y = (unsigned)f2bf(r.z-bf2f(h2)) | ((unsigned)f2bf(r.w-bf2f(h3))<<16);
    *(uint2*)&oh[base] = hp;
    *(uint2*)&ol[base] = lp;
  }
}

// --------- conv5 + pool via MFMA: pooled[b,o] = max_n relu(bn(Σ_c w5[o,c] h[c,n])) ---------
__global__ __launch_bounds__(256, 2) void conv5_mfma_kernel(
      const unsigned short* __restrict__ hTh, const unsigned short* __restrict__ hTl,
      const float* __restrict__ w5, const float* __restrict__ bnp,
      float* __restrict__ pooled){
  __shared__ __align__(16) unsigned short wh[64][128], wl[64][128];  // 32 KB
  __shared__ __align__(16) unsigned short hh[64][128], hl[64][128];  // 32 KB
  const int id = blockIdx.x;                 // id = (b%8) + 8*inner + 512*(b/8)
  const int b  = (id & 7) + ((id >> 9) << 3);
  const int inner = (id >> 3) & 63;
  const int o0 = (inner & 15) * 64;
  const int nb = (inner >> 4) * (NN/4);
  const int t = threadIdx.x;
  const int l = t & 63, w = t >> 6;
  const int rw = w & 1, cw = w >> 1;
  const int fc = l & 15, g = l >> 4;
  const unsigned swr = (unsigned)((fc & 7) << 4);
  #pragma unroll
  for (int i = 0; i < 8; ++i){
    int idx = t + 256*i;                     // 2048 float4
    int row = idx >> 5, c0 = (idx & 31) * 4;
    float4 v = *(const float4*)(w5 + (size_t)(o0 + row)*128 + c0);
    unsigned short h0=f2bf(v.x), h1=f2bf(v.y), h2=f2bf(v.z), h3=f2bf(v.w);
    uint2 hp, lp;
    hp.x = (unsigned)h0 | ((unsigned)h1<<16);
    hp.y = (unsigned)h2 | ((unsigned)h3<<16);
    lp.x = (unsigned)f2bf(v.x-bf2f(h0)) | ((unsigned)f2bf(v.y-bf2f(h1))<<16);
    lp.y = (unsigned)f2bf(v.z-bf2f(h2)) | ((unsigned)f2bf(v.w-bf2f(h3))<<16);
    unsigned off = (unsigned)(row*256) + (((unsigned)(c0*2)) ^ ((unsigned)((row&7)<<4)));
    *(uint2*)((char*)wh + off) = hp;
    *(uint2*)((char*)wl + off) = lp;
  }
  float sc[2][4], sh[2][4];
  #pragma unroll
  for (int i = 0; i < 2; ++i){
    #pragma unroll
    for (int r = 0; r < 4; ++r){
      int o = o0 + rw*32 + i*16 + g*4 + r;
      float gg = bnp[o], be = bnp[1024+o], mn = bnp[2048+o], vv = bnp[3072+o];
      sc[i][r] = gg * rsqrtf(vv + BN_EPS_);
      sh[i][r] = be - mn*sc[i][r];
    }
  }
  float vmax[2][4] = {{0.f,0.f,0.f,0.f},{0.f,0.f,0.f,0.f}};
  const unsigned short* hb = hTh + (size_t)b*NN*128;
  const unsigned short* lb = hTl + (size_t)b*NN*128;
  for (int nt = 0; nt < (NN/4)/64; ++nt){
    const int n0 = nb + nt*64;
    __syncthreads();
    #pragma unroll
    for (int i = 0; i < 4; ++i){
      int idx = t + 256*i;                  // 1024 uint4 per buffer
      int row = idx >> 4, sl = idx & 15;
      unsigned off = (unsigned)(row*256) + ((unsigned)((sl << 4) ^ ((row&7)<<4)));
      *(uint4*)((char*)hh + off) = *(const uint4*)(hb + (size_t)(n0+row)*128 + sl*8);
      *(uint4*)((char*)hl + off) = *(const uint4*)(lb + (size_t)(n0+row)*128 + sl*8);
    }
    __syncthreads();
    f32x4 acc[2][2];
    #pragma unroll
    for (int i = 0; i < 2; ++i){ acc[i][0] = (f32x4){0.f,0.f,0.f,0.f}; acc[i][1] = (f32x4){0.f,0.f,0.f,0.f}; }
    #pragma unroll
    for (int kk = 0; kk < 4; ++kk){
      unsigned ko = ((unsigned)((kk*32 + g*8)*2)) ^ swr;
      short8v aih[2], ail[2], bih[2], bil[2];
      #pragma unroll
      for (int i = 0; i < 2; ++i){
        unsigned aoff = (unsigned)((rw*32 + i*16 + fc)*256) + ko;
        aih[i] = *(const short8v*)((const char*)wh + aoff);
        ail[i] = *(const short8v*)((const char*)wl + aoff);
      }
      #pragma unroll
      for (int ct = 0; ct < 2; ++ct){
        unsigned boff = (unsigned)((cw*32 + ct*16 + fc)*256) + ko;
        bih[ct] = *(const short8v*)((const char*)hh + boff);
        bil[ct] = *(const short8v*)((const char*)hl + boff);
      }
      #pragma unroll
      for (int i = 0; i < 2; ++i){
        #pragma unroll
        for (int ct = 0; ct < 2; ++ct){
          acc[i][ct] = __builtin_amdgcn_mfma_f32_16x16x32_bf16(aih[i], bih[ct], acc[i][ct], 0, 0, 0);
          acc[i][ct] = __builtin_amdgcn_mfma_f32_16x16x32_bf16(aih[i], bil[ct], acc[i][ct], 0, 0, 0);
          acc[i][ct] = __builtin_amdgcn_mfma_f32_16x16x32_bf16(ail[i], bih[ct], acc[i][ct], 0, 0, 0);
        }
      }
    }
    #pragma unroll
    for (int i = 0; i < 2; ++i){
      #pragma unroll
      for (int ct = 0; ct < 2; ++ct){
        #pragma unroll
        for (int r = 0; r < 4; ++r){
          float y = sc[i][r]*acc[i][ct][r] + sh[i][r];
          y = fmaxf(y, 0.0f);
          vmax[i][r] = fmaxf(vmax[i][r], y);
        }
      }
    }
  }
  #pragma unroll
  for (int i = 0; i < 2; ++i){
    #pragma unroll
    for (int r = 0; r < 4; ++r){
      float v = vmax[i][r];
      v = fmaxf(v, __shfl_xor(v, 1));
      v = fmaxf(v, __shfl_xor(v, 2));
      v = fmaxf(v, __shfl_xor(v, 4));
      v = fmaxf(v, __shfl_xor(v, 8));
      if (fc == 0)
        atomicMax((unsigned int*)&pooled[b*1024 + o0 + rw*32 + i*16 + g*4 + r],
                  __float_as_uint(v));
    }
  }
}

// --------- lin1 + bn6 + relu ---------
__global__ void lin1_kernel(const float* __restrict__ pooled, const float* __restrict__ w,
      const float* __restrict__ bnp, float* __restrict__ out1){
  int tid = blockIdx.x*256 + threadIdx.x;
  int b = tid >> 9, j = tid & 511;
  const float4* p4 = (const float4*)(pooled + b*1024);
  const float4* w4 = (const float4*)(w + j*1024);
  float sum = 0.0f;
  for (int e = 0; e < 256; ++e){
    float4 a = p4[e], c = w4[e];
    sum += a.x*c.x + a.y*c.y + a.z*c.z + a.w*c.w;
  }
  float g = bnp[j], be = bnp[512+j], mn = bnp[2*512+j], vv = bnp[3*512+j];
  float s = g * rsqrtf(vv + BN_EPS_);
  float y = s*sum + (be - mn*s);
  out1[b*512 + j] = fmaxf(y, 0.0f);
}

// --------- lin2 ---------
__global__ void lin2_kernel(const float* __restrict__ h, const float* __restrict__ w,
      const float* __restrict__ bias, float* __restrict__ out){
  int tid = blockIdx.x*64 + threadIdx.x;
  if (tid >= 640) return;
  int b = tid / 40, k = tid % 40;
  const float4* h4 = (const float4*)(h + b*512);
  const float4* w4 = (const float4*)(w + k*512);
  float sum = 0.0f;
  for (int e = 0; e < 128; ++e){
    float4 a = h4[e], c = w4[e];
    sum += a.x*c.x + a.y*c.y + a.z*c.z + a.w*c.w;
  }
  out[tid] = sum + bias[k];
}

extern "C" void kernel_launch(void* const* d_in, const int* in_sizes, int n_in,
                              void* d_out, int out_size, void* d_ws, size_t ws_size,
                              hipStream_t stream){
  (void)in_sizes; (void)n_in; (void)out_size; (void)ws_size;
  const float* x     = (const float*)d_in[0];
  const float* w1    = (const float*)d_in[1];
  const float* w2    = (const float*)d_in[2];
  const float* w3    = (const float*)d_in[3];
  const float* w4    = (const float*)d_in[4];
  const float* w5    = (const float*)d_in[5];
  const float* bn1   = (const float*)d_in[6];
  const float* bn2   = (const float*)d_in[7];
  const float* bn3   = (const float*)d_in[8];
  const float* bn4   = (const float*)d_in[9];
  const float* bn5   = (const float*)d_in[10];
  const float* da_wqk[4] = {(const float*)d_in[11], (const float*)d_in[15], (const float*)d_in[19], (const float*)d_in[23]};
  const float* da_wt[4]  = {(const float*)d_in[12], (const float*)d_in[16], (const float*)d_in[20], (const float*)d_in[24]};
  const float* da_bt[4]  = {(const float*)d_in[13], (const float*)d_in[17], (const float*)d_in[21], (const float*)d_in[25]};
  const float* da_bn[4]  = {(const float*)d_in[14], (const float*)d_in[18], (const float*)d_in[22], (const float*)d_in[26]};
  const float* lin1_w = (const float*)d_in[27];
  const float* bn6    = (const float*)d_in[28];
  const float* lin2_w = (const float*)d_in[29];
  const float* lin2_b = (const float*)d_in[30];

  float* ws = (float*)d_ws;
  float* maxval = ws;                   // 1 float (padded to 64)
  float* dens   = ws + 64;
  float* zinv4  = dens + BB*NN;                     // 4 layers' zinv
  float* hA     = zinv4 + 4*(size_t)BB*NN;
  float* hB     = hA  + (size_t)BB*64*NN;
  float* h4A    = hB  + (size_t)BB*64*NN;
  unsigned short* raw = (unsigned short*)(h4A + (size_t)BB*128*NN);  // 2 bf16 halves, RA=144
  float* pooled = (float*)raw + (size_t)BB*144*NN;
  float* l1o    = pooled + BB*1024;
  float* blockmax = l1o + BB*512;               // 4096 floats
  unsigned short* Ah = (unsigned short*)(blockmax + 4096);   // BB*128*NN bf16
  unsigned short* Al = Ah + (size_t)BB*128*NN;
  float* h4B    = hA;   // (unused in TP mode; kept for signature)

  density7_kernel<<<dim3(NN/DG, BB), 512, 0, stream>>>(x, dens, blockmax);
  finalize_max_kernel<<<dim3(1), 256, 0, stream>>>(blockmax, maxval);
  zrow4_kernel<<<dim3(32,BB), 256, 0, stream>>>(dens, maxval,
      da_wqk[0], da_wqk[1], da_wqk[2], da_wqk[3], zinv4);

  conv_bn_relu_kernel<3,64><<<dim3(32,BB),256,0,stream>>>(x, w1, bn1, hA, Ah, Al);

  // attn1: hA -> hB
  attn_mfma_kernel<64><<<dim3(1024),256,0,stream>>>(Ah, Al, dens, zinv4, da_wqk[0], 16, maxval, raw);
  attn_post_kernel<64,false><<<dim3(32,BB),256,0,stream>>>(hA, raw, da_wt[0], da_bt[0], da_bn[0], hB, nullptr, nullptr);

  conv_bn_relu_kernel<64,64><<<dim3(32,BB),256,0,stream>>>(hB, w2, bn2, hA, Ah, Al);

  // attn2: hA -> hB
  attn_mfma_kernel<64><<<dim3(1024),256,0,stream>>>(Ah, Al, dens, zinv4 + (size_t)BB*NN, da_wqk[1], 16, maxval, raw);
  attn_post_kernel<64,false><<<dim3(32,BB),256,0,stream>>>(hA, raw, da_wt[1], da_bt[1], da_bn[1], hB, nullptr, nullptr);

  conv_bn_relu_kernel<64,64><<<dim3(32,BB),256,0,stream>>>(hB, w3, bn3, hA, Ah, Al);

  // attn3: hA -> hB
  attn_mfma_kernel<64><<<dim3(1024),256,0,stream>>>(Ah, Al, dens, zinv4 + 2*(size_t)BB*NN, da_wqk[2], 16, maxval, raw);
  attn_post_kernel<64,false><<<dim3(32,BB),256,0,stream>>>(hA, raw, da_wt[2], da_bt[2], da_bn[2], hB, nullptr, nullptr);

  conv_bn_relu_kernel<64,128><<<dim3(32,BB),256,0,stream>>>(hB, w4, bn4, h4A, Ah, Al);

  // attn4 (C=128): h4A -> hT (transposed bf16 hi/lo, reusing Ah/Al after attn4_mfma)
  attn_mfma_kernel<128><<<dim3(1024),256,0,stream>>>(Ah, Al, dens, zinv4 + 3*(size_t)BB*NN, da_wqk[3], 32, maxval, raw);
  attn_post_kernel<128,true><<<dim3(32,BB),256,0,stream>>>(h4A, raw, da_wt[3], da_bt[3], da_bn[3], h4B, Ah, Al);

  hipMemsetAsync(pooled, 0, BB*1024*sizeof(float), stream);
  conv5_mfma_kernel<<<dim3(1024),256,0,stream>>>(Ah, Al, w5, bn5, pooled);
  lin1_kernel<<<dim3(32),256,0,stream>>>(pooled, lin1_w, bn6, l1o);
  lin2_kernel<<<dim3(10),64,0,stream>>>(l1o, lin2_w, lin2_b, (float*)d_out);
}